// Round 3
// baseline (1421.981 us; speedup 1.0000x reference)
//
#include <hip/hip_runtime.h>

#define GRIDW 512
#define RCH 16                          // channels per plane
#define TEXELS (GRIDW * GRIDW)          // 262144
#define PLANE_ELEMS (RCH * TEXELS)      // 4194304 floats per plane

typedef float f32x4 __attribute__((ext_vector_type(4)));  // native vec for nt builtins

// ---------------------------------------------------------------------------
// Kernel 1: transpose each plane [16, 512, 512] -> [512, 512, 16]
// One thread per texel: 16 coalesced strided reads (nt), 4 float4 stores.
// ---------------------------------------------------------------------------
__global__ __launch_bounds__(256) void transpose_planes_k(
    const float* __restrict__ p0, const float* __restrict__ p1,
    const float* __restrict__ p2, float* __restrict__ outT) {
  int bid = blockIdx.x;
  int plane = bid >> 10;                       // 1024 blocks of 256 per plane
  int t = ((bid & 1023) << 8) + threadIdx.x;   // texel index h*512+w
  const float* __restrict__ src = (plane == 0) ? p0 : (plane == 1) ? p1 : p2;
  float v[RCH];
#pragma unroll
  for (int r = 0; r < RCH; ++r)
    v[r] = __builtin_nontemporal_load(src + (size_t)r * TEXELS + t);
  f32x4* dst = reinterpret_cast<f32x4*>(outT + (size_t)plane * PLANE_ELEMS +
                                        (size_t)t * RCH);
#pragma unroll
  for (int c = 0; c < 4; ++c) {
    f32x4 q = {v[4 * c + 0], v[4 * c + 1], v[4 * c + 2], v[4 * c + 3]};
    dst[c] = q;
  }
}

// ---------------------------------------------------------------------------
// Bilinear helpers (faithful to grid_sample align_corners=True, zeros padding)
// ---------------------------------------------------------------------------
__device__ __forceinline__ void axis_corners(float u, int& i0, int& i1,
                                             float& w0, float& w1) {
  float h = (u + 1.0f) * 0.5f * (float)(GRIDW - 1);
  float hf = floorf(h);
  float d = h - hf;
  int a = (int)hf;
  int b = a + 1;
  w0 = (a >= 0 && a < GRIDW) ? (1.0f - d) : 0.0f;
  w1 = (b >= 0 && b < GRIDW) ? d : 0.0f;
  i0 = min(max(a, 0), GRIDW - 1);
  i1 = min(max(b, 0), GRIDW - 1);
}

// Sample one transposed plane [512][512][16] at (u->h, v->w); out = 16 floats.
__device__ __forceinline__ void sample_plane_t(const f32x4* __restrict__ pT,
                                               float u, float v, f32x4 out[4]) {
  int h0, h1, w0, w1;
  float a0, a1, b0, b1;
  axis_corners(u, h0, h1, a0, a1);
  axis_corners(v, w0, w1, b0, b1);
  float W00 = a0 * b0, W01 = a0 * b1, W10 = a1 * b0, W11 = a1 * b1;
  const f32x4* p00 = pT + (size_t)(h0 * GRIDW + w0) * 4;
  const f32x4* p01 = pT + (size_t)(h0 * GRIDW + w1) * 4;
  const f32x4* p10 = pT + (size_t)(h1 * GRIDW + w0) * 4;
  const f32x4* p11 = pT + (size_t)(h1 * GRIDW + w1) * 4;
#pragma unroll
  for (int c = 0; c < 4; ++c) {
    out[c] = W00 * p00[c] + W01 * p01[c] + W10 * p10[c] + W11 * p11[c];
  }
}

// ---------------------------------------------------------------------------
// Kernel 2: main sampler. One thread per point. Output stores are
// non-temporal: 403 MB write-once stream must not evict plane data from L2.
// ---------------------------------------------------------------------------
__global__ __launch_bounds__(256) void sample_k(
    const float* __restrict__ xyz, const float* __restrict__ planesT,
    const float* __restrict__ mn, const float* __restrict__ mx,
    float* __restrict__ out, int n) {
  int i = blockIdx.x * 256 + threadIdx.x;
  if (i >= n) return;
  float x = xyz[3 * i + 0];
  float y = xyz[3 * i + 1];
  float z = xyz[3 * i + 2];
  float nx = (x - mn[0]) / (mx[0] - mn[0]) * 2.0f - 1.0f;
  float ny = (y - mn[1]) / (mx[1] - mn[1]) * 2.0f - 1.0f;
  float nz = (z - mn[2]) / (mx[2] - mn[2]) * 2.0f - 1.0f;

  f32x4 res[12];
  const f32x4* pT = reinterpret_cast<const f32x4*>(planesT);
  sample_plane_t(pT + 0 * (PLANE_ELEMS / 4), nx, ny, &res[0]);  // xy
  sample_plane_t(pT + 1 * (PLANE_ELEMS / 4), nx, nz, &res[4]);  // xz
  sample_plane_t(pT + 2 * (PLANE_ELEMS / 4), ny, nz, &res[8]);  // yz

  f32x4* o = reinterpret_cast<f32x4*>(out + (size_t)i * 48);
#pragma unroll
  for (int k = 0; k < 12; ++k) __builtin_nontemporal_store(res[k], o + k);
}

// ---------------------------------------------------------------------------
// Fallback (ws too small): direct gather from [16,512,512] planes. Slow, correct.
// ---------------------------------------------------------------------------
__global__ __launch_bounds__(256) void sample_direct_k(
    const float* __restrict__ xyz, const float* __restrict__ p0,
    const float* __restrict__ p1, const float* __restrict__ p2,
    const float* __restrict__ mn, const float* __restrict__ mx,
    float* __restrict__ out, int n) {
  int i = blockIdx.x * 256 + threadIdx.x;
  if (i >= n) return;
  float c3[3];
#pragma unroll
  for (int d = 0; d < 3; ++d)
    c3[d] = (xyz[3 * i + d] - mn[d]) / (mx[d] - mn[d]) * 2.0f - 1.0f;
  const float* planes[3] = {p0, p1, p2};
  const int ui[3] = {0, 0, 1};  // u coord per plane: nx, nx, ny
  const int vi[3] = {1, 2, 2};  // v coord per plane: ny, nz, nz
  for (int p = 0; p < 3; ++p) {
    int h0, h1, w0, w1;
    float a0, a1, b0, b1;
    axis_corners(c3[ui[p]], h0, h1, a0, a1);
    axis_corners(c3[vi[p]], w0, w1, b0, b1);
    float W00 = a0 * b0, W01 = a0 * b1, W10 = a1 * b0, W11 = a1 * b1;
    const float* pl = planes[p];
    int t00 = h0 * GRIDW + w0, t01 = h0 * GRIDW + w1;
    int t10 = h1 * GRIDW + w0, t11 = h1 * GRIDW + w1;
#pragma unroll
    for (int r = 0; r < RCH; ++r) {
      const float* base = pl + (size_t)r * TEXELS;
      float val = W00 * base[t00] + W01 * base[t01] + W10 * base[t10] +
                  W11 * base[t11];
      out[(size_t)i * 48 + p * RCH + r] = val;
    }
  }
}

extern "C" void kernel_launch(void* const* d_in, const int* in_sizes, int n_in,
                              void* d_out, int out_size, void* d_ws,
                              size_t ws_size, hipStream_t stream) {
  const float* xyz = (const float*)d_in[0];
  const float* xy_plane = (const float*)d_in[1];
  const float* xz_plane = (const float*)d_in[2];
  const float* yz_plane = (const float*)d_in[3];
  const float* mn = (const float*)d_in[4];
  const float* mx = (const float*)d_in[5];
  float* out = (float*)d_out;
  int n = in_sizes[0] / 3;

  size_t need = (size_t)3 * PLANE_ELEMS * sizeof(float);  // 50.3 MB
  if (ws_size >= need) {
    float* planesT = (float*)d_ws;
    transpose_planes_k<<<3 * (TEXELS / 256), 256, 0, stream>>>(
        xy_plane, xz_plane, yz_plane, planesT);
    sample_k<<<(n + 255) / 256, 256, 0, stream>>>(xyz, planesT, mn, mx, out, n);
  } else {
    sample_direct_k<<<(n + 255) / 256, 256, 0, stream>>>(
        xyz, xy_plane, xz_plane, yz_plane, mn, mx, out, n);
  }
}

// Round 4
// 1244.416 us; speedup vs baseline: 1.1427x; 1.1427x over previous
//
#include <hip/hip_runtime.h>

#define GRIDW 512
#define RCH 16                          // channels per plane
#define TEXELS (GRIDW * GRIDW)          // 262144
#define PLANE_ELEMS (RCH * TEXELS)      // 4194304 floats per plane

typedef float f32x4 __attribute__((ext_vector_type(4)));

// ---------------------------------------------------------------------------
// Kernel 1: transpose each plane [16, 512, 512] -> [512, 512, 16]
// One thread per texel: 16 coalesced strided reads (nt: read-once), 4 vec4 stores.
// ---------------------------------------------------------------------------
__global__ __launch_bounds__(256) void transpose_planes_k(
    const float* __restrict__ p0, const float* __restrict__ p1,
    const float* __restrict__ p2, float* __restrict__ outT) {
  int bid = blockIdx.x;
  int plane = bid >> 10;                       // 1024 blocks of 256 per plane
  int t = ((bid & 1023) << 8) + threadIdx.x;   // texel index h*512+w
  const float* __restrict__ src = (plane == 0) ? p0 : (plane == 1) ? p1 : p2;
  float v[RCH];
#pragma unroll
  for (int r = 0; r < RCH; ++r)
    v[r] = __builtin_nontemporal_load(src + (size_t)r * TEXELS + t);
  f32x4* dst = reinterpret_cast<f32x4*>(outT + (size_t)plane * PLANE_ELEMS +
                                        (size_t)t * RCH);
#pragma unroll
  for (int c = 0; c < 4; ++c) {
    f32x4 q = {v[4 * c + 0], v[4 * c + 1], v[4 * c + 2], v[4 * c + 3]};
    dst[c] = q;
  }
}

// ---------------------------------------------------------------------------
// Bilinear helpers (faithful to grid_sample align_corners=True, zeros padding)
// ---------------------------------------------------------------------------
__device__ __forceinline__ void axis_corners(float u, int& i0, int& i1,
                                             float& w0, float& w1) {
  float h = (u + 1.0f) * 0.5f * (float)(GRIDW - 1);
  float hf = floorf(h);
  float d = h - hf;
  int a = (int)hf;
  int b = a + 1;
  w0 = (a >= 0 && a < GRIDW) ? (1.0f - d) : 0.0f;
  w1 = (b >= 0 && b < GRIDW) ? d : 0.0f;
  i0 = min(max(a, 0), GRIDW - 1);
  i1 = min(max(b, 0), GRIDW - 1);
}

// Sample one transposed plane [512][512][16] at (u->h, v->w); out = 16 floats.
__device__ __forceinline__ void sample_plane_t(const f32x4* __restrict__ pT,
                                               float u, float v, f32x4 out[4]) {
  int h0, h1, w0, w1;
  float a0, a1, b0, b1;
  axis_corners(u, h0, h1, a0, a1);
  axis_corners(v, w0, w1, b0, b1);
  float W00 = a0 * b0, W01 = a0 * b1, W10 = a1 * b0, W11 = a1 * b1;
  const f32x4* p00 = pT + (size_t)(h0 * GRIDW + w0) * 4;
  const f32x4* p01 = pT + (size_t)(h0 * GRIDW + w1) * 4;
  const f32x4* p10 = pT + (size_t)(h1 * GRIDW + w0) * 4;
  const f32x4* p11 = pT + (size_t)(h1 * GRIDW + w1) * 4;
#pragma unroll
  for (int c = 0; c < 4; ++c) {
    out[c] = W00 * p00[c] + W01 * p01[c] + W10 * p10[c] + W11 * p11[c];
  }
}

// ---------------------------------------------------------------------------
// Kernel 2: main sampler. One thread per point. Plain stores: the write-back
// L2 merges each thread's 192 contiguous bytes into full lines (nt stores
// measured 3x write amplification: partial sectors bypass L2 unmerged).
// ---------------------------------------------------------------------------
__global__ __launch_bounds__(256) void sample_k(
    const float* __restrict__ xyz, const float* __restrict__ planesT,
    const float* __restrict__ mn, const float* __restrict__ mx,
    float* __restrict__ out, int n) {
  int i = blockIdx.x * 256 + threadIdx.x;
  if (i >= n) return;
  float x = xyz[3 * i + 0];
  float y = xyz[3 * i + 1];
  float z = xyz[3 * i + 2];
  float nx = (x - mn[0]) / (mx[0] - mn[0]) * 2.0f - 1.0f;
  float ny = (y - mn[1]) / (mx[1] - mn[1]) * 2.0f - 1.0f;
  float nz = (z - mn[2]) / (mx[2] - mn[2]) * 2.0f - 1.0f;

  f32x4 res[12];
  const f32x4* pT = reinterpret_cast<const f32x4*>(planesT);
  sample_plane_t(pT + 0 * (PLANE_ELEMS / 4), nx, ny, &res[0]);  // xy
  sample_plane_t(pT + 1 * (PLANE_ELEMS / 4), nx, nz, &res[4]);  // xz
  sample_plane_t(pT + 2 * (PLANE_ELEMS / 4), ny, nz, &res[8]);  // yz

  f32x4* o = reinterpret_cast<f32x4*>(out + (size_t)i * 48);
#pragma unroll
  for (int k = 0; k < 12; ++k) o[k] = res[k];
}

// ---------------------------------------------------------------------------
// Fallback (ws too small): direct gather from [16,512,512] planes. Slow, correct.
// ---------------------------------------------------------------------------
__global__ __launch_bounds__(256) void sample_direct_k(
    const float* __restrict__ xyz, const float* __restrict__ p0,
    const float* __restrict__ p1, const float* __restrict__ p2,
    const float* __restrict__ mn, const float* __restrict__ mx,
    float* __restrict__ out, int n) {
  int i = blockIdx.x * 256 + threadIdx.x;
  if (i >= n) return;
  float c3[3];
#pragma unroll
  for (int d = 0; d < 3; ++d)
    c3[d] = (xyz[3 * i + d] - mn[d]) / (mx[d] - mn[d]) * 2.0f - 1.0f;
  const float* planes[3] = {p0, p1, p2};
  const int ui[3] = {0, 0, 1};  // u coord per plane: nx, nx, ny
  const int vi[3] = {1, 2, 2};  // v coord per plane: ny, nz, nz
  for (int p = 0; p < 3; ++p) {
    int h0, h1, w0, w1;
    float a0, a1, b0, b1;
    axis_corners(c3[ui[p]], h0, h1, a0, a1);
    axis_corners(c3[vi[p]], w0, w1, b0, b1);
    float W00 = a0 * b0, W01 = a0 * b1, W10 = a1 * b0, W11 = a1 * b1;
    const float* pl = planes[p];
    int t00 = h0 * GRIDW + w0, t01 = h0 * GRIDW + w1;
    int t10 = h1 * GRIDW + w0, t11 = h1 * GRIDW + w1;
#pragma unroll
    for (int r = 0; r < RCH; ++r) {
      const float* base = pl + (size_t)r * TEXELS;
      float val = W00 * base[t00] + W01 * base[t01] + W10 * base[t10] +
                  W11 * base[t11];
      out[(size_t)i * 48 + p * RCH + r] = val;
    }
  }
}

extern "C" void kernel_launch(void* const* d_in, const int* in_sizes, int n_in,
                              void* d_out, int out_size, void* d_ws,
                              size_t ws_size, hipStream_t stream) {
  const float* xyz = (const float*)d_in[0];
  const float* xy_plane = (const float*)d_in[1];
  const float* xz_plane = (const float*)d_in[2];
  const float* yz_plane = (const float*)d_in[3];
  const float* mn = (const float*)d_in[4];
  const float* mx = (const float*)d_in[5];
  float* out = (float*)d_out;
  int n = in_sizes[0] / 3;

  size_t need = (size_t)3 * PLANE_ELEMS * sizeof(float);  // 50.3 MB
  if (ws_size >= need) {
    float* planesT = (float*)d_ws;
    transpose_planes_k<<<3 * (TEXELS / 256), 256, 0, stream>>>(
        xy_plane, xz_plane, yz_plane, planesT);
    sample_k<<<(n + 255) / 256, 256, 0, stream>>>(xyz, planesT, mn, mx, out, n);
  } else {
    sample_direct_k<<<(n + 255) / 256, 256, 0, stream>>>(
        xyz, xy_plane, xz_plane, yz_plane, mn, mx, out, n);
  }
}